// Round 10
// baseline (149.007 us; speedup 1.0000x reference)
//
#include <hip/hip_runtime.h>

#define B_    64
#define T_    512
#define DIN   512
#define DHID  1024
#define DOUT  512
#define NDAYS 24

typedef unsigned short u16;
typedef __bf16 bf16x8 __attribute__((ext_vector_type(8)));
typedef u16    u16x8  __attribute__((ext_vector_type(8)));
typedef float  f32x4  __attribute__((ext_vector_type(4)));

static __device__ __forceinline__ u16 f2bf(float f) {
    union { float f; unsigned u; } v; v.f = f;
    unsigned r = v.u + 0x7FFFu + ((v.u >> 16) & 1u);
    return (u16)(r >> 16);
}
static __device__ __forceinline__ float bf2f(u16 h) {
    union { unsigned u; float f; } v; v.u = ((unsigned)h) << 16;
    return v.f;
}

static __device__ __forceinline__ void gload_lds16(const void* g, void* l) {
    __builtin_amdgcn_global_load_lds(
        (const __attribute__((address_space(1))) void*)g,
        (__attribute__((address_space(3))) void*)l, 16, 0, 0);
}

// 64x64-tile transpose body: W[d][R][C] fp32 -> WT[d][C][R] bf16.
// Reads 256B contiguous per 16-lane row; writes 128B contiguous per 8-lane
// row (u16x8). LDS [64][65]: 65 = 1 mod 32 -> <=2-way bank alias (free).
static __device__ __forceinline__ void transpose64_body(
    const float* __restrict__ W, u16* __restrict__ WT,
    int R, int C, int j, int tid)
{
    __shared__ float t[64][65];
    const int gx = C >> 6, gy = R >> 6;
    const int bx = j % gx;
    const int by = (j / gx) % gy;
    const int d  = j / (gx * gy);
    const int r0 = by * 64, c0 = bx * 64;
    const float* Wd = W + (size_t)d * R * C;
    u16* WTd = WT + (size_t)d * R * C;

#pragma unroll
    for (int i = 0; i < 4; ++i) {
        const int row = i * 16 + (tid >> 4);
        const int col = (tid & 15) * 4;
        const float4 v = *(const float4*)&Wd[(size_t)(r0 + row) * C + c0 + col];
        t[row][col]     = v.x;
        t[row][col + 1] = v.y;
        t[row][col + 2] = v.z;
        t[row][col + 3] = v.w;
    }
    __syncthreads();
#pragma unroll
    for (int p = 0; p < 2; ++p) {
        const int c  = p * 32 + (tid >> 3);
        const int rs = (tid & 7) * 8;
        u16x8 o;
#pragma unroll
        for (int k = 0; k < 8; ++k) o[k] = f2bf(t[rs + k][c]);
        *(u16x8*)&WTd[(size_t)(c0 + c) * R + r0 + rs] = o;
    }
}

// standalone 64x64 transpose (small-ws fallback for W2)
__global__ __launch_bounds__(256)
void transpose64(const float* __restrict__ W, u16* __restrict__ WT, int R, int C) {
    transpose64_body(W, WT, R, C, blockIdx.x, threadIdx.x);
}

// Merged aux: W1 transpose [0,3072) + optional W2 transpose [3072,3072+nW2)
// + x fp32->bf16 cvt (rest).
__global__ __launch_bounds__(256)
void aux_prep(const float* __restrict__ W1, u16* __restrict__ W1T,
              const float* __restrict__ W2, u16* __restrict__ W2T,
              const float* __restrict__ x, u16* __restrict__ xb,
              int nW2)
{
    const int jb = blockIdx.x;
    const int tid = threadIdx.x;
    constexpr int NW1 = NDAYS * (DIN / 64) * (DHID / 64);   // 3072
    if (jb < NW1) {
        transpose64_body(W1, W1T, DIN, DHID, jb, tid);
    } else if (jb < NW1 + nW2) {
        transpose64_body(W2, W2T, DHID, DOUT, jb - NW1, tid);
    } else {
        const int n8 = B_ * T_ * DIN / 8;
        const int ncvt = gridDim.x - NW1 - nW2;
        int i = (jb - NW1 - nW2) * 256 + tid;
        const int stride = ncvt * 256;
        for (; i < n8; i += stride) {
            float4 a = ((const float4*)x)[i * 2];
            float4 b = ((const float4*)x)[i * 2 + 1];
            u16x8 p;
            p[0] = f2bf(a.x); p[1] = f2bf(a.y); p[2] = f2bf(a.z); p[3] = f2bf(a.w);
            p[4] = f2bf(b.x); p[5] = f2bf(b.y); p[6] = f2bf(b.z); p[7] = f2bf(b.w);
            ((u16x8*)xb)[i] = p;
        }
    }
}

// ---------------- GEMM1: 256x256-tile 8-phase, SNAKE quadrant order --------
// (round-9 proven, unchanged)
template<int MT, int NT, int KT, bool RELU, bool OUT_BF16>
__global__ __launch_bounds__(512, 1)
void gemm8(const u16* __restrict__ Aall,
           const u16* __restrict__ BT,      // [NDAYS][NT][KT]
           const float* __restrict__ bias,  // [NDAYS][NT]
           const int* __restrict__ didx,
           void* __restrict__ Call)
{
    constexpr int GX = MT / 256;
    constexpr int GY = NT / 256;
    constexpr int NWG = GX * GY * B_;
    constexpr int NT_K = KT / 64;
    static_assert(NT_K >= 2 && (NWG % 8) == 0, "geometry");

    constexpr int Q = NWG / 8;
    const int hw = blockIdx.x;
    const int l  = (hw & 7) * Q + (hw >> 3);
    const int bx = l % GX;
    const int by = (l / GX) % GY;
    const int bz = l / (GX * GY);

    const int day = didx[bz];
    const int m0 = bx * 256, n0 = by * 256;
    const int tid = threadIdx.x;
    const int wv = tid >> 6, ln = tid & 63;
    const int wm = wv >> 2, wn = wv & 3;

    __shared__ __align__(16) u16 sA[2][256 * 64];
    __shared__ __align__(16) u16 sB[2][256 * 64];

    const u16* Ab = Aall + (size_t)bz * MT * KT + (size_t)m0 * KT;
    const u16* Bt = BT + (size_t)day * NT * KT + (size_t)n0 * KT;

    auto stageA = [&](int buf, int t, int h) {
#pragma unroll
        for (int c = 0; c < 2; ++c) {
            const int rl = h * 128 + wv * 16 + c * 8 + (ln >> 3);
            const int cd = (ln & 7) ^ (rl & 7);
            gload_lds16(Ab + (size_t)rl * KT + t * 64 + cd * 8,
                        (char*)&sA[buf][(h * 128 + wv * 16 + c * 8) * 64]);
        }
    };
    auto stageB = [&](int buf, int t, int h) {
#pragma unroll
        for (int c = 0; c < 2; ++c) {
            const int rl = h * 128 + wv * 16 + c * 8 + (ln >> 3);
            const int cd = (ln & 7) ^ (rl & 7);
            gload_lds16(Bt + (size_t)rl * KT + t * 64 + cd * 8,
                        (char*)&sB[buf][(h * 128 + wv * 16 + c * 8) * 64]);
        }
    };

    f32x4 acc[8][4];
#pragma unroll
    for (int i = 0; i < 8; ++i)
#pragma unroll
        for (int j = 0; j < 4; ++j)
            acc[i][j] = (f32x4){0.f, 0.f, 0.f, 0.f};

    stageA(0, 0, 0); stageB(0, 0, 0); stageA(0, 0, 1); stageB(0, 0, 1);
    stageA(1, 1, 0); stageB(1, 1, 0);
    asm volatile("s_waitcnt vmcnt(4)" ::: "memory");
    __builtin_amdgcn_s_barrier();

    for (int t = 0; t < NT_K; ++t) {
        const int buf = t & 1;
        const u16* sAb = sA[buf];
        const u16* sBb = sB[buf];
        bf16x8 av0[2][4], av1[2][4], bv0[2][2], bv1[2][2];

        auto readAv = [&](bf16x8 (&dst)[2][4], int mq) {
#pragma unroll
            for (int ks = 0; ks < 2; ++ks)
#pragma unroll
                for (int mi = 0; mi < 4; ++mi) {
                    const int r = mq * 128 + wm * 64 + mi * 16 + (ln & 15);
                    const int slot = (ks * 4 + (ln >> 4)) ^ (r & 7);
                    dst[ks][mi] = *(const bf16x8*)&sAb[r * 64 + slot * 8];
                }
        };
        auto readBv = [&](bf16x8 (&dst)[2][2], int nq) {
#pragma unroll
            for (int ks = 0; ks < 2; ++ks)
#pragma unroll
                for (int ni = 0; ni < 2; ++ni) {
                    const int r = nq * 128 + wn * 32 + ni * 16 + (ln & 15);
                    const int slot = (ks * 4 + (ln >> 4)) ^ (r & 7);
                    dst[ks][ni] = *(const bf16x8*)&sBb[r * 64 + slot * 8];
                }
        };
        auto mfmaQ = [&](bf16x8 (&a)[2][4], bf16x8 (&b)[2][2], int mq, int nq) {
#pragma unroll
            for (int ks = 0; ks < 2; ++ks)
#pragma unroll
                for (int mi = 0; mi < 4; ++mi)
#pragma unroll
                    for (int ni = 0; ni < 2; ++ni)
                        acc[mq * 4 + mi][nq * 2 + ni] =
                            __builtin_amdgcn_mfma_f32_16x16x32_bf16(
                                a[ks][mi], b[ks][ni],
                                acc[mq * 4 + mi][nq * 2 + ni], 0, 0, 0);
        };

        // phase 0: (0,0)
        readAv(av0, 0); readBv(bv0, 0);
        if (t + 1 < NT_K) stageA(buf ^ 1, t + 1, 1);
        __builtin_amdgcn_s_barrier();
        asm volatile("s_waitcnt lgkmcnt(0)" ::: "memory");
        __builtin_amdgcn_sched_barrier(0);
        __builtin_amdgcn_s_setprio(1);
        mfmaQ(av0, bv0, 0, 0);
        __builtin_amdgcn_s_setprio(0);
        __builtin_amdgcn_s_barrier();

        // phase 1: (1,0) — hold bv0
        readAv(av1, 1);
        if (t + 1 < NT_K) stageB(buf ^ 1, t + 1, 1);
        __builtin_amdgcn_s_barrier();
        asm volatile("s_waitcnt lgkmcnt(0)" ::: "memory");
        __builtin_amdgcn_sched_barrier(0);
        __builtin_amdgcn_s_setprio(1);
        mfmaQ(av1, bv0, 1, 0);
        __builtin_amdgcn_s_setprio(0);
        __builtin_amdgcn_s_barrier();

        // phase 2: (1,1) — hold av1
        readBv(bv1, 1);
        if (t + 2 < NT_K) stageA(buf, t + 2, 0);
        __builtin_amdgcn_s_barrier();
        asm volatile("s_waitcnt lgkmcnt(0)" ::: "memory");
        __builtin_amdgcn_sched_barrier(0);
        __builtin_amdgcn_s_setprio(1);
        mfmaQ(av1, bv1, 1, 1);
        __builtin_amdgcn_s_setprio(0);
        __builtin_amdgcn_s_barrier();

        // phase 3: (0,1) — no ds_reads (av0, bv1 held)
        if (t + 2 < NT_K) stageB(buf, t + 2, 0);
        __builtin_amdgcn_s_barrier();
        asm volatile("s_waitcnt lgkmcnt(0)" ::: "memory");
        __builtin_amdgcn_sched_barrier(0);
        __builtin_amdgcn_s_setprio(1);
        mfmaQ(av0, bv1, 0, 1);
        __builtin_amdgcn_s_setprio(0);
        if (t + 2 < NT_K) asm volatile("s_waitcnt vmcnt(4)" ::: "memory");
        else              asm volatile("s_waitcnt vmcnt(0)" ::: "memory");
        __builtin_amdgcn_s_barrier();
    }

    const float* bs = bias + (size_t)day * NT + n0;
#pragma unroll
    for (int nq = 0; nq < 2; ++nq)
#pragma unroll
        for (int ni = 0; ni < 2; ++ni) {
            const int col = nq * 128 + wn * 32 + ni * 16 + (ln & 15);
            const float bval = bs[col];
#pragma unroll
            for (int mq = 0; mq < 2; ++mq)
#pragma unroll
                for (int mi = 0; mi < 4; ++mi)
#pragma unroll
                    for (int i = 0; i < 4; ++i) {
                        const int row = mq * 128 + wm * 64 + mi * 16 + (ln >> 4) * 4 + i;
                        float v = acc[mq * 4 + mi][nq * 2 + ni][i] + bval;
                        if (RELU) v = fmaxf(v, 0.f);
                        const size_t off = (size_t)bz * MT * NT + (size_t)(m0 + row) * NT + (n0 + col);
                        if (OUT_BF16) ((u16*)Call)[off] = f2bf(v);
                        else          ((float*)Call)[off] = v;
                    }
        }
}

// ------------- GEMM2 + fused LayerNorm (proven round-5 version) ------------
__global__ __launch_bounds__(512, 1)
void gemm2_ln(const u16* __restrict__ Aall,   // h [B][T][DHID] bf16
              const u16* __restrict__ BT,     // W2T [NDAYS][DOUT][DHID] bf16
              const float* __restrict__ bias, // b2 [NDAYS][DOUT]
              const int* __restrict__ didx,
              const float* __restrict__ gamma,
              const float* __restrict__ beta,
              float* __restrict__ out)        // [B][T][DOUT] fp32
{
    constexpr int BM = 128, BK = 64;
    constexpr int KT = DHID;
    constexpr int NT_K = KT / BK;       // 16
    constexpr int GX = T_ / BM;         // 4
    constexpr int NWG = GX * B_;        // 256

    constexpr int Q = NWG / 8;
    const int hw = blockIdx.x;
    const int l  = (hw & 7) * Q + (hw >> 3);
    const int bx = l % GX;
    const int bz = l / GX;

    const int day = didx[bz];
    const int m0 = bx * BM;
    const int tid = threadIdx.x;
    const int wv = tid >> 6, ln = tid & 63;
    const int wm = wv >> 2, wn = wv & 3;   // 2 x 4

    __shared__ __align__(16) u16 sA[2][BM * BK];    // 32 KB
    __shared__ __align__(16) u16 sB[2][DOUT * BK];  // 128 KB

    const u16* Ab = Aall + (size_t)bz * T_ * KT + (size_t)m0 * KT;
    const u16* Bt = BT + (size_t)day * DOUT * KT;

    auto stageA = [&](int buf, int t) {
#pragma unroll
        for (int c = 0; c < 2; ++c) {
            const int rl = wv * 16 + c * 8 + (ln >> 3);
            const int cd = (ln & 7) ^ (rl & 7);
            gload_lds16(Ab + (size_t)rl * KT + t * BK + cd * 8,
                        (char*)&sA[buf][(wv * 16 + c * 8) * BK]);
        }
    };
    auto stageBh = [&](int buf, int t, int h) {
#pragma unroll
        for (int c = 0; c < 4; ++c) {
            const int rl = h * 256 + wv * 32 + c * 8 + (ln >> 3);
            const int cd = (ln & 7) ^ (rl & 7);
            gload_lds16(Bt + (size_t)rl * KT + t * BK + cd * 8,
                        (char*)&sB[buf][(h * 256 + wv * 32 + c * 8) * BK]);
        }
    };

    f32x4 acc[4][8];
#pragma unroll
    for (int i = 0; i < 4; ++i)
#pragma unroll
        for (int j = 0; j < 8; ++j)
            acc[i][j] = (f32x4){0.f, 0.f, 0.f, 0.f};

    stageA(0, 0); stageBh(0, 0, 0); stageBh(0, 0, 1);
    stageA(1, 1); stageBh(1, 1, 0);
    asm volatile("s_waitcnt vmcnt(6)" ::: "memory");
    __builtin_amdgcn_s_barrier();

    for (int t = 0; t < NT_K; ++t) {
        const int buf = t & 1;
        const u16* sAb = sA[buf];
        const u16* sBb = sB[buf];
        bf16x8 av[2][4], bv[2][2];

#pragma unroll
        for (int p = 0; p < 4; ++p) {
            if (p == 0) {   // ONLY p0 — sA[buf] is overwritten by p1's stage
#pragma unroll
                for (int ks = 0; ks < 2; ++ks)
#pragma unroll
                    for (int mi = 0; mi < 4; ++mi) {
                        const int r = wm * 64 + mi * 16 + (ln & 15);
                        const int slot = (ks * 4 + (ln >> 4)) ^ (r & 7);
                        av[ks][mi] = *(const bf16x8*)&sAb[r * BK + slot * 8];
                    }
            }
#pragma unroll
            for (int ks = 0; ks < 2; ++ks)
#pragma unroll
                for (int ni = 0; ni < 2; ++ni) {
                    const int r = p * 128 + wn * 32 + ni * 16 + (ln & 15);
                    const int slot = (ks * 4 + (ln >> 4)) ^ (r & 7);
                    bv[ks][ni] = *(const bf16x8*)&sBb[r * BK + slot * 8];
                }
            if (p == 0)      { if (t + 1 < NT_K) stageBh(buf ^ 1, t + 1, 1); }
            else if (p == 1) { if (t + 2 < NT_K) stageA(buf, t + 2); }
            else if (p == 2) { if (t + 2 < NT_K) stageBh(buf, t + 2, 0); }

            __builtin_amdgcn_s_barrier();
            asm volatile("s_waitcnt lgkmcnt(0)" ::: "memory");
            __builtin_amdgcn_sched_barrier(0);
            __builtin_amdgcn_s_setprio(1);
#pragma unroll
            for (int ks = 0; ks < 2; ++ks)
#pragma unroll
                for (int mi = 0; mi < 4; ++mi)
#pragma unroll
                    for (int ni = 0; ni < 2; ++ni)
                        acc[mi][p * 2 + ni] =
                            __builtin_amdgcn_mfma_f32_16x16x32_bf16(
                                av[ks][mi], bv[ks][ni], acc[mi][p * 2 + ni], 0, 0, 0);
            __builtin_amdgcn_s_setprio(0);
            if (p == 3) {
                if (t + 2 < NT_K) asm volatile("s_waitcnt vmcnt(6)" ::: "memory");
                else              asm volatile("s_waitcnt vmcnt(0)" ::: "memory");
            }
            __builtin_amdgcn_s_barrier();
        }
    }

    // ---- epilogue stage 1: y = acc + bias -> bf16 -> LDS (acc dies here) --
    const float* bs = bias + (size_t)day * DOUT;
    float bval[8];
#pragma unroll
    for (int f = 0; f < 8; ++f)
        bval[f] = bs[(f >> 1) * 128 + wn * 32 + (f & 1) * 16 + (ln & 15)];

    u16* yb = (u16*)&sB[0][0];   // [128][512] bf16 = 128 KB (both dead bufs)
#pragma unroll
    for (int mi = 0; mi < 4; ++mi)
#pragma unroll
        for (int f = 0; f < 8; ++f) {
            const int col = (f >> 1) * 128 + wn * 32 + (f & 1) * 16 + (ln & 15);
#pragma unroll
            for (int i = 0; i < 4; ++i) {
                const int rloc = wm * 64 + mi * 16 + (ln >> 4) * 4 + i;
                yb[rloc * DOUT + col] = f2bf(acc[mi][f][i] + bval[f]);
            }
        }
    __syncthreads();

    // ---- epilogue stage 2: per-wave rowwise LayerNorm ----
    const float* gs = gamma + (size_t)day * DOUT;
    const float* es = beta + (size_t)day * DOUT;
    const float4 g0 = ((const float4*)gs)[ln * 2];
    const float4 g1 = ((const float4*)gs)[ln * 2 + 1];
    const float4 e0 = ((const float4*)es)[ln * 2];
    const float4 e1 = ((const float4*)es)[ln * 2 + 1];

    float* op = out + (size_t)bz * T_ * DOUT + (size_t)m0 * DOUT;
#pragma unroll 4
    for (int r = wv * 16; r < wv * 16 + 16; ++r) {
        const u16x8 yv = *(const u16x8*)&yb[r * DOUT + ln * 8];
        float yf[8];
#pragma unroll
        for (int j = 0; j < 8; ++j) yf[j] = bf2f(yv[j]);
        float s = 0.f, q = 0.f;
#pragma unroll
        for (int j = 0; j < 8; ++j) { s += yf[j]; q += yf[j] * yf[j]; }
#pragma unroll
        for (int o = 32; o; o >>= 1) { s += __shfl_xor(s, o); q += __shfl_xor(q, o); }
        const float mean = s * (1.f / 512.f);
        const float var  = q * (1.f / 512.f) - mean * mean;
        const float rstd = rsqrtf(var + 1e-5f);
        float4 o0, o1;
        o0.x = (yf[0] - mean) * rstd * g0.x + e0.x;
        o0.y = (yf[1] - mean) * rstd * g0.y + e0.y;
        o0.z = (yf[2] - mean) * rstd * g0.z + e0.z;
        o0.w = (yf[3] - mean) * rstd * g0.w + e0.w;
        o1.x = (yf[4] - mean) * rstd * g1.x + e1.x;
        o1.y = (yf[5] - mean) * rstd * g1.y + e1.y;
        o1.z = (yf[6] - mean) * rstd * g1.z + e1.z;
        o1.w = (yf[7] - mean) * rstd * g1.w + e1.w;
        ((float4*)(op + (size_t)r * DOUT))[ln * 2] = o0;
        ((float4*)(op + (size_t)r * DOUT))[ln * 2 + 1] = o1;
    }
}

extern "C" void kernel_launch(void* const* d_in, const int* in_sizes, int n_in,
                              void* d_out, int out_size, void* d_ws, size_t ws_size,
                              hipStream_t stream)
{
    const float* x     = (const float*)d_in[0];
    const int*   didx  = (const int*)d_in[1];
    const float* W1    = (const float*)d_in[2];
    const float* b1    = (const float*)d_in[3];
    const float* W2    = (const float*)d_in[4];
    const float* b2    = (const float*)d_in[5];
    const float* gamma = (const float*)d_in[6];
    const float* beta  = (const float*)d_in[7];
    float* out = (float*)d_out;

    char* ws = (char*)d_ws;
    u16* W1T = (u16*)ws;                       // [24][1024][512] bf16 = 25.2 MB
    u16* h   = (u16*)(ws + 25165824);          // [64][512][1024] bf16 = 67.1 MB
    u16* xb  = (u16*)(ws + 92274688);          // [64][512][512]  bf16 = 33.6 MB

    const bool bigws = ws_size >= 150994944ULL;  // room for separate W2T region
    constexpr int NW = NDAYS * (DIN / 64) * (DHID / 64);   // 3072 per weight

    if (bigws) {
        u16* W2T = (u16*)(ws + 125829120);     // [24][512][1024] bf16 = 25.2 MB
        aux_prep<<<NW * 2 + 2048, 256, 0, stream>>>(W1, W1T, W2, W2T, x, xb, NW);
        gemm8<T_, DHID, DIN, true, true>
            <<<dim3(2 * 4 * B_), 512, 0, stream>>>(xb, W1T, b1, didx, h);
        gemm2_ln<<<dim3(4 * B_), 512, 0, stream>>>(h, W2T, b2, didx, gamma, beta, out);
    } else {
        u16* W2T = xb;                         // overlay xb AFTER gemm1
        aux_prep<<<NW + 2048, 256, 0, stream>>>(W1, W1T, W2, W2T, x, xb, 0);
        gemm8<T_, DHID, DIN, true, true>
            <<<dim3(2 * 4 * B_), 512, 0, stream>>>(xb, W1T, b1, didx, h);
        transpose64<<<NW, 256, 0, stream>>>(W2, W2T, DHID, DOUT);
        gemm2_ln<<<dim3(4 * B_), 512, 0, stream>>>(h, W2T, b2, didx, gamma, beta, out);
    }
}

// Round 11
// 143.634 us; speedup vs baseline: 1.0374x; 1.0374x over previous
//
#include <hip/hip_runtime.h>

#define B_    64
#define T_    512
#define DIN   512
#define DHID  1024
#define DOUT  512
#define NDAYS 24

typedef unsigned short u16;
typedef __bf16 bf16x8 __attribute__((ext_vector_type(8)));
typedef u16    u16x8  __attribute__((ext_vector_type(8)));
typedef float  f32x4  __attribute__((ext_vector_type(4)));

static __device__ __forceinline__ u16 f2bf(float f) {
    union { float f; unsigned u; } v; v.f = f;
    unsigned r = v.u + 0x7FFFu + ((v.u >> 16) & 1u);
    return (u16)(r >> 16);
}
static __device__ __forceinline__ float bf2f(u16 h) {
    union { unsigned u; float f; } v; v.u = ((unsigned)h) << 16;
    return v.f;
}

static __device__ __forceinline__ void gload_lds16(const void* g, void* l) {
    __builtin_amdgcn_global_load_lds(
        (const __attribute__((address_space(1))) void*)g,
        (__attribute__((address_space(3))) void*)l, 16, 0, 0);
}

// 64x64-tile transpose body: W[d][R][C] fp32 -> WT[d][C][R] bf16.
static __device__ __forceinline__ void transpose64_body(
    const float* __restrict__ W, u16* __restrict__ WT,
    int R, int C, int j, int tid)
{
    __shared__ float t[64][65];
    const int gx = C >> 6, gy = R >> 6;
    const int bx = j % gx;
    const int by = (j / gx) % gy;
    const int d  = j / (gx * gy);
    const int r0 = by * 64, c0 = bx * 64;
    const float* Wd = W + (size_t)d * R * C;
    u16* WTd = WT + (size_t)d * R * C;

#pragma unroll
    for (int i = 0; i < 4; ++i) {
        const int row = i * 16 + (tid >> 4);
        const int col = (tid & 15) * 4;
        const float4 v = *(const float4*)&Wd[(size_t)(r0 + row) * C + c0 + col];
        t[row][col]     = v.x;
        t[row][col + 1] = v.y;
        t[row][col + 2] = v.z;
        t[row][col + 3] = v.w;
    }
    __syncthreads();
#pragma unroll
    for (int p = 0; p < 2; ++p) {
        const int c  = p * 32 + (tid >> 3);
        const int rs = (tid & 7) * 8;
        u16x8 o;
#pragma unroll
        for (int k = 0; k < 8; ++k) o[k] = f2bf(t[rs + k][c]);
        *(u16x8*)&WTd[(size_t)(c0 + c) * R + r0 + rs] = o;
    }
}

__global__ __launch_bounds__(256)
void transpose64(const float* __restrict__ W, u16* __restrict__ WT, int R, int C) {
    transpose64_body(W, WT, R, C, blockIdx.x, threadIdx.x);
}

// Merged aux: W1 transpose + optional W2 transpose + x fp32->bf16 cvt
__global__ __launch_bounds__(256)
void aux_prep(const float* __restrict__ W1, u16* __restrict__ W1T,
              const float* __restrict__ W2, u16* __restrict__ W2T,
              const float* __restrict__ x, u16* __restrict__ xb,
              int nW2)
{
    const int jb = blockIdx.x;
    const int tid = threadIdx.x;
    constexpr int NW1 = NDAYS * (DIN / 64) * (DHID / 64);   // 3072
    if (jb < NW1) {
        transpose64_body(W1, W1T, DIN, DHID, jb, tid);
    } else if (jb < NW1 + nW2) {
        transpose64_body(W2, W2T, DHID, DOUT, jb - NW1, tid);
    } else {
        const int n8 = B_ * T_ * DIN / 8;
        const int ncvt = gridDim.x - NW1 - nW2;
        int i = (jb - NW1 - nW2) * 256 + tid;
        const int stride = ncvt * 256;
        for (; i < n8; i += stride) {
            float4 a = ((const float4*)x)[i * 2];
            float4 b = ((const float4*)x)[i * 2 + 1];
            u16x8 p;
            p[0] = f2bf(a.x); p[1] = f2bf(a.y); p[2] = f2bf(a.z); p[3] = f2bf(a.w);
            p[4] = f2bf(b.x); p[5] = f2bf(b.y); p[6] = f2bf(b.z); p[7] = f2bf(b.w);
            ((u16x8*)xb)[i] = p;
        }
    }
}

// -------- GEMM1: 256x256 tile, snake order, MERGED to 2 phases/K-tile ------
// P0 = quadrants (0,0)+(1,0): read av0,av1,bv0; stage {A,B}(t+1,h1).
// P1 = quadrants (1,1)+(0,1): read bv1; stage {A,B}(t+2,h0); gate vmcnt(4)
//   (outstanding after issue = {A,B}(t+1,h1):4 + {A,B}(t+2,h0):4 = 8;
//    vmcnt(4) forces tile t+1 fully landed before next P0 reads buf^1).
// Liveness: P1's h0 stage targets were read only at P0 (drained by P0's
// lgkmcnt + end barrier); P1 reads h1 regions only. 4 barriers/tile (was 8).
template<int MT, int NT, int KT, bool RELU, bool OUT_BF16>
__global__ __launch_bounds__(512, 1)
void gemm8(const u16* __restrict__ Aall,
           const u16* __restrict__ BT,      // [NDAYS][NT][KT]
           const float* __restrict__ bias,  // [NDAYS][NT]
           const int* __restrict__ didx,
           void* __restrict__ Call)
{
    constexpr int GX = MT / 256;
    constexpr int GY = NT / 256;
    constexpr int NWG = GX * GY * B_;
    constexpr int NT_K = KT / 64;
    static_assert(NT_K >= 2 && (NWG % 8) == 0, "geometry");

    constexpr int Q = NWG / 8;
    const int hw = blockIdx.x;
    const int l  = (hw & 7) * Q + (hw >> 3);
    const int bx = l % GX;
    const int by = (l / GX) % GY;
    const int bz = l / (GX * GY);

    const int day = didx[bz];
    const int m0 = bx * 256, n0 = by * 256;
    const int tid = threadIdx.x;
    const int wv = tid >> 6, ln = tid & 63;
    const int wm = wv >> 2, wn = wv & 3;

    __shared__ __align__(16) u16 sA[2][256 * 64];
    __shared__ __align__(16) u16 sB[2][256 * 64];

    const u16* Ab = Aall + (size_t)bz * MT * KT + (size_t)m0 * KT;
    const u16* Bt = BT + (size_t)day * NT * KT + (size_t)n0 * KT;

    auto stageA = [&](int buf, int t, int h) {
#pragma unroll
        for (int c = 0; c < 2; ++c) {
            const int rl = h * 128 + wv * 16 + c * 8 + (ln >> 3);
            const int cd = (ln & 7) ^ (rl & 7);
            gload_lds16(Ab + (size_t)rl * KT + t * 64 + cd * 8,
                        (char*)&sA[buf][(h * 128 + wv * 16 + c * 8) * 64]);
        }
    };
    auto stageB = [&](int buf, int t, int h) {
#pragma unroll
        for (int c = 0; c < 2; ++c) {
            const int rl = h * 128 + wv * 16 + c * 8 + (ln >> 3);
            const int cd = (ln & 7) ^ (rl & 7);
            gload_lds16(Bt + (size_t)rl * KT + t * 64 + cd * 8,
                        (char*)&sB[buf][(h * 128 + wv * 16 + c * 8) * 64]);
        }
    };

    f32x4 acc[8][4];
#pragma unroll
    for (int i = 0; i < 8; ++i)
#pragma unroll
        for (int j = 0; j < 4; ++j)
            acc[i][j] = (f32x4){0.f, 0.f, 0.f, 0.f};

    stageA(0, 0, 0); stageB(0, 0, 0); stageA(0, 0, 1); stageB(0, 0, 1);
    stageA(1, 1, 0); stageB(1, 1, 0);
    asm volatile("s_waitcnt vmcnt(4)" ::: "memory");
    __builtin_amdgcn_s_barrier();

    for (int t = 0; t < NT_K; ++t) {
        const int buf = t & 1;
        const u16* sAb = sA[buf];
        const u16* sBb = sB[buf];
        bf16x8 av0[2][4], av1[2][4], bv0[2][2], bv1[2][2];

        auto readAv = [&](bf16x8 (&dst)[2][4], int mq) {
#pragma unroll
            for (int ks = 0; ks < 2; ++ks)
#pragma unroll
                for (int mi = 0; mi < 4; ++mi) {
                    const int r = mq * 128 + wm * 64 + mi * 16 + (ln & 15);
                    const int slot = (ks * 4 + (ln >> 4)) ^ (r & 7);
                    dst[ks][mi] = *(const bf16x8*)&sAb[r * 64 + slot * 8];
                }
        };
        auto readBv = [&](bf16x8 (&dst)[2][2], int nq) {
#pragma unroll
            for (int ks = 0; ks < 2; ++ks)
#pragma unroll
                for (int ni = 0; ni < 2; ++ni) {
                    const int r = nq * 128 + wn * 32 + ni * 16 + (ln & 15);
                    const int slot = (ks * 4 + (ln >> 4)) ^ (r & 7);
                    dst[ks][ni] = *(const bf16x8*)&sBb[r * 64 + slot * 8];
                }
        };
        auto mfmaQ = [&](bf16x8 (&a)[2][4], bf16x8 (&b)[2][2], int mq, int nq) {
#pragma unroll
            for (int ks = 0; ks < 2; ++ks)
#pragma unroll
                for (int mi = 0; mi < 4; ++mi)
#pragma unroll
                    for (int ni = 0; ni < 2; ++ni)
                        acc[mq * 4 + mi][nq * 2 + ni] =
                            __builtin_amdgcn_mfma_f32_16x16x32_bf16(
                                a[ks][mi], b[ks][ni],
                                acc[mq * 4 + mi][nq * 2 + ni], 0, 0, 0);
        };

        // ---- P0: (0,0) + (1,0) ----
        readAv(av0, 0); readAv(av1, 1); readBv(bv0, 0);
        if (t + 1 < NT_K) { stageA(buf ^ 1, t + 1, 1); stageB(buf ^ 1, t + 1, 1); }
        __builtin_amdgcn_s_barrier();
        asm volatile("s_waitcnt lgkmcnt(0)" ::: "memory");
        __builtin_amdgcn_sched_barrier(0);
        __builtin_amdgcn_s_setprio(1);
        mfmaQ(av0, bv0, 0, 0);
        mfmaQ(av1, bv0, 1, 0);
        __builtin_amdgcn_s_setprio(0);
        __builtin_amdgcn_s_barrier();

        // ---- P1: (1,1) + (0,1) ----
        readBv(bv1, 1);
        if (t + 2 < NT_K) { stageA(buf, t + 2, 0); stageB(buf, t + 2, 0); }
        __builtin_amdgcn_s_barrier();
        asm volatile("s_waitcnt lgkmcnt(0)" ::: "memory");
        __builtin_amdgcn_sched_barrier(0);
        __builtin_amdgcn_s_setprio(1);
        mfmaQ(av1, bv1, 1, 1);
        mfmaQ(av0, bv1, 0, 1);
        __builtin_amdgcn_s_setprio(0);
        if (t + 2 < NT_K) asm volatile("s_waitcnt vmcnt(4)" ::: "memory");
        else              asm volatile("s_waitcnt vmcnt(0)" ::: "memory");
        __builtin_amdgcn_s_barrier();
    }

    const float* bs = bias + (size_t)day * NT + n0;
#pragma unroll
    for (int nq = 0; nq < 2; ++nq)
#pragma unroll
        for (int ni = 0; ni < 2; ++ni) {
            const int col = nq * 128 + wn * 32 + ni * 16 + (ln & 15);
            const float bval = bs[col];
#pragma unroll
            for (int mq = 0; mq < 2; ++mq)
#pragma unroll
                for (int mi = 0; mi < 4; ++mi)
#pragma unroll
                    for (int i = 0; i < 4; ++i) {
                        const int row = mq * 128 + wm * 64 + mi * 16 + (ln >> 4) * 4 + i;
                        float v = acc[mq * 4 + mi][nq * 2 + ni][i] + bval;
                        if (RELU) v = fmaxf(v, 0.f);
                        const size_t off = (size_t)bz * MT * NT + (size_t)(m0 + row) * NT + (n0 + col);
                        if (OUT_BF16) ((u16*)Call)[off] = f2bf(v);
                        else          ((float*)Call)[off] = v;
                    }
        }
}

// ---- GEMM2 + fused LN, MERGED to 2 phases/K-tile ----
// P0 = col-halves {0,1}: read av + bv01; stage Bh1(t+1).
// P1 = col-halves {2,3}: read bv23 (h1 rows); stage A(t+2)+Bh0(t+2);
//   gate vmcnt(5) (outstanding = Bh1(t+1):4 + A(t+2):1 + Bh0(t+2):4 = 9).
__global__ __launch_bounds__(512, 1)
void gemm2_ln(const u16* __restrict__ Aall,   // h [B][T][DHID] bf16
              const u16* __restrict__ BT,     // W2T [NDAYS][DOUT][DHID] bf16
              const float* __restrict__ bias, // b2 [NDAYS][DOUT]
              const int* __restrict__ didx,
              const float* __restrict__ gamma,
              const float* __restrict__ beta,
              float* __restrict__ out)        // [B][T][DOUT] fp32
{
    constexpr int BM = 128, BK = 64;
    constexpr int KT = DHID;
    constexpr int NT_K = KT / BK;       // 16
    constexpr int GX = T_ / BM;         // 4
    constexpr int NWG = GX * B_;        // 256

    constexpr int Q = NWG / 8;
    const int hw = blockIdx.x;
    const int l  = (hw & 7) * Q + (hw >> 3);
    const int bx = l % GX;
    const int bz = l / GX;

    const int day = didx[bz];
    const int m0 = bx * BM;
    const int tid = threadIdx.x;
    const int wv = tid >> 6, ln = tid & 63;
    const int wm = wv >> 2, wn = wv & 3;   // 2 x 4

    __shared__ __align__(16) u16 sA[2][BM * BK];    // 32 KB
    __shared__ __align__(16) u16 sB[2][DOUT * BK];  // 128 KB

    const u16* Ab = Aall + (size_t)bz * T_ * KT + (size_t)m0 * KT;
    const u16* Bt = BT + (size_t)day * DOUT * KT;

    auto stageA = [&](int buf, int t) {
#pragma unroll
        for (int c = 0; c < 2; ++c) {
            const int rl = wv * 16 + c * 8 + (ln >> 3);
            const int cd = (ln & 7) ^ (rl & 7);
            gload_lds16(Ab + (size_t)rl * KT + t * BK + cd * 8,
                        (char*)&sA[buf][(wv * 16 + c * 8) * BK]);
        }
    };
    auto stageBh = [&](int buf, int t, int h) {
#pragma unroll
        for (int c = 0; c < 4; ++c) {
            const int rl = h * 256 + wv * 32 + c * 8 + (ln >> 3);
            const int cd = (ln & 7) ^ (rl & 7);
            gload_lds16(Bt + (size_t)rl * KT + t * BK + cd * 8,
                        (char*)&sB[buf][(h * 256 + wv * 32 + c * 8) * BK]);
        }
    };

    f32x4 acc[4][8];
#pragma unroll
    for (int i = 0; i < 4; ++i)
#pragma unroll
        for (int j = 0; j < 8; ++j)
            acc[i][j] = (f32x4){0.f, 0.f, 0.f, 0.f};

    stageA(0, 0); stageBh(0, 0, 0); stageBh(0, 0, 1);
    stageA(1, 1); stageBh(1, 1, 0);
    asm volatile("s_waitcnt vmcnt(5)" ::: "memory");
    __builtin_amdgcn_s_barrier();

    for (int t = 0; t < NT_K; ++t) {
        const int buf = t & 1;
        const u16* sAb = sA[buf];
        const u16* sBb = sB[buf];
        bf16x8 av[2][4], bvA[2][2], bvB[2][2];

        auto readBv = [&](bf16x8 (&dst)[2][2], int nq) {
#pragma unroll
            for (int ks = 0; ks < 2; ++ks)
#pragma unroll
                for (int ni = 0; ni < 2; ++ni) {
                    const int r = nq * 128 + wn * 32 + ni * 16 + (ln & 15);
                    const int slot = (ks * 4 + (ln >> 4)) ^ (r & 7);
                    dst[ks][ni] = *(const bf16x8*)&sBb[r * BK + slot * 8];
                }
        };
        auto mfmaQ = [&](bf16x8 (&b)[2][2], int nq) {
#pragma unroll
            for (int ks = 0; ks < 2; ++ks)
#pragma unroll
                for (int mi = 0; mi < 4; ++mi)
#pragma unroll
                    for (int ni = 0; ni < 2; ++ni)
                        acc[mi][nq * 2 + ni] =
                            __builtin_amdgcn_mfma_f32_16x16x32_bf16(
                                av[ks][mi], b[ks][ni],
                                acc[mi][nq * 2 + ni], 0, 0, 0);
        };

        // ---- P0: col-halves 0,1 ----
#pragma unroll
        for (int ks = 0; ks < 2; ++ks)
#pragma unroll
            for (int mi = 0; mi < 4; ++mi) {
                const int r = wm * 64 + mi * 16 + (ln & 15);
                const int slot = (ks * 4 + (ln >> 4)) ^ (r & 7);
                av[ks][mi] = *(const bf16x8*)&sAb[r * BK + slot * 8];
            }
        readBv(bvA, 0); readBv(bvB, 1);
        if (t + 1 < NT_K) stageBh(buf ^ 1, t + 1, 1);
        __builtin_amdgcn_s_barrier();
        asm volatile("s_waitcnt lgkmcnt(0)" ::: "memory");
        __builtin_amdgcn_sched_barrier(0);
        __builtin_amdgcn_s_setprio(1);
        mfmaQ(bvA, 0);
        mfmaQ(bvB, 1);
        __builtin_amdgcn_s_setprio(0);
        __builtin_amdgcn_s_barrier();

        // ---- P1: col-halves 2,3 ----
        readBv(bvA, 2); readBv(bvB, 3);
        if (t + 2 < NT_K) { stageA(buf, t + 2); stageBh(buf, t + 2, 0); }
        __builtin_amdgcn_s_barrier();
        asm volatile("s_waitcnt lgkmcnt(0)" ::: "memory");
        __builtin_amdgcn_sched_barrier(0);
        __builtin_amdgcn_s_setprio(1);
        mfmaQ(bvA, 2);
        mfmaQ(bvB, 3);
        __builtin_amdgcn_s_setprio(0);
        if (t + 2 < NT_K) asm volatile("s_waitcnt vmcnt(5)" ::: "memory");
        else              asm volatile("s_waitcnt vmcnt(0)" ::: "memory");
        __builtin_amdgcn_s_barrier();
    }

    // ---- epilogue stage 1: y = acc + bias -> bf16 -> LDS (acc dies here) --
    const float* bs = bias + (size_t)day * DOUT;
    float bval[8];
#pragma unroll
    for (int f = 0; f < 8; ++f)
        bval[f] = bs[(f >> 1) * 128 + wn * 32 + (f & 1) * 16 + (ln & 15)];

    u16* yb = (u16*)&sB[0][0];   // [128][512] bf16 = 128 KB (both dead bufs)
#pragma unroll
    for (int mi = 0; mi < 4; ++mi)
#pragma unroll
        for (int f = 0; f < 8; ++f) {
            const int col = (f >> 1) * 128 + wn * 32 + (f & 1) * 16 + (ln & 15);
#pragma unroll
            for (int i = 0; i < 4; ++i) {
                const int rloc = wm * 64 + mi * 16 + (ln >> 4) * 4 + i;
                yb[rloc * DOUT + col] = f2bf(acc[mi][f][i] + bval[f]);
            }
        }
    __syncthreads();

    // ---- epilogue stage 2: per-wave rowwise LayerNorm ----
    const float* gs = gamma + (size_t)day * DOUT;
    const float* es = beta + (size_t)day * DOUT;
    const float4 g0 = ((const float4*)gs)[ln * 2];
    const float4 g1 = ((const float4*)gs)[ln * 2 + 1];
    const float4 e0 = ((const float4*)es)[ln * 2];
    const float4 e1 = ((const float4*)es)[ln * 2 + 1];

    float* op = out + (size_t)bz * T_ * DOUT + (size_t)m0 * DOUT;
#pragma unroll 4
    for (int r = wv * 16; r < wv * 16 + 16; ++r) {
        const u16x8 yv = *(const u16x8*)&yb[r * DOUT + ln * 8];
        float yf[8];
#pragma unroll
        for (int j = 0; j < 8; ++j) yf[j] = bf2f(yv[j]);
        float s = 0.f, q = 0.f;
#pragma unroll
        for (int j = 0; j < 8; ++j) { s += yf[j]; q += yf[j] * yf[j]; }
#pragma unroll
        for (int o = 32; o; o >>= 1) { s += __shfl_xor(s, o); q += __shfl_xor(q, o); }
        const float mean = s * (1.f / 512.f);
        const float var  = q * (1.f / 512.f) - mean * mean;
        const float rstd = rsqrtf(var + 1e-5f);
        float4 o0, o1;
        o0.x = (yf[0] - mean) * rstd * g0.x + e0.x;
        o0.y = (yf[1] - mean) * rstd * g0.y + e0.y;
        o0.z = (yf[2] - mean) * rstd * g0.z + e0.z;
        o0.w = (yf[3] - mean) * rstd * g0.w + e0.w;
        o1.x = (yf[4] - mean) * rstd * g1.x + e1.x;
        o1.y = (yf[5] - mean) * rstd * g1.y + e1.y;
        o1.z = (yf[6] - mean) * rstd * g1.z + e1.z;
        o1.w = (yf[7] - mean) * rstd * g1.w + e1.w;
        ((float4*)(op + (size_t)r * DOUT))[ln * 2] = o0;
        ((float4*)(op + (size_t)r * DOUT))[ln * 2 + 1] = o1;
    }
}

extern "C" void kernel_launch(void* const* d_in, const int* in_sizes, int n_in,
                              void* d_out, int out_size, void* d_ws, size_t ws_size,
                              hipStream_t stream)
{
    const float* x     = (const float*)d_in[0];
    const int*   didx  = (const int*)d_in[1];
    const float* W1    = (const float*)d_in[2];
    const float* b1    = (const float*)d_in[3];
    const float* W2    = (const float*)d_in[4];
    const float* b2    = (const float*)d_in[5];
    const float* gamma = (const float*)d_in[6];
    const float* beta  = (const float*)d_in[7];
    float* out = (float*)d_out;

    char* ws = (char*)d_ws;
    u16* W1T = (u16*)ws;                       // [24][1024][512] bf16 = 25.2 MB
    u16* h   = (u16*)(ws + 25165824);          // [64][512][1024] bf16 = 67.1 MB
    u16* xb  = (u16*)(ws + 92274688);          // [64][512][512]  bf16 = 33.6 MB

    const bool bigws = ws_size >= 150994944ULL;  // room for separate W2T region
    constexpr int NW = NDAYS * (DIN / 64) * (DHID / 64);   // 3072 per weight

    if (bigws) {
        u16* W2T = (u16*)(ws + 125829120);     // [24][512][1024] bf16 = 25.2 MB
        aux_prep<<<NW * 2 + 2048, 256, 0, stream>>>(W1, W1T, W2, W2T, x, xb, NW);
        gemm8<T_, DHID, DIN, true, true>
            <<<dim3(2 * 4 * B_), 512, 0, stream>>>(xb, W1T, b1, didx, h);
        gemm2_ln<<<dim3(4 * B_), 512, 0, stream>>>(h, W2T, b2, didx, gamma, beta, out);
    } else {
        u16* W2T = xb;                         // overlay xb AFTER gemm1
        aux_prep<<<NW + 2048, 256, 0, stream>>>(W1, W1T, W2, W2T, x, xb, 0);
        gemm8<T_, DHID, DIN, true, true>
            <<<dim3(2 * 4 * B_), 512, 0, stream>>>(xb, W1T, b1, didx, h);
        transpose64<<<NW, 256, 0, stream>>>(W2, W2T, DHID, DOUT);
        gemm2_ln<<<dim3(4 * B_), 512, 0, stream>>>(h, W2T, b2, didx, gamma, beta, out);
    }
}